// Round 4
// baseline (11918.269 us; speedup 1.0000x reference)
//
#include <hip/hip_runtime.h>
#include <hip/hip_bf16.h>
#include <math.h>

// QRNN quantum-circuit simulator, 16 qubits, B=256, T=32.
// State layout: float2 S[bb][s], s = h*256 + l; qubit j<8 <-> bit j of l,
// qubit 8+k <-> bit k of h. bb indexes the current 128-batch chunk (the two
// chunks are independent and reuse the same 64MB workspace -> L3-resident).
//
// Circuit regrouping (gates on disjoint qubits commute):
//   evolution = Prod_t [ D * (A_t (x) B) ],  B time-independent
//   -> kernels:  H_0<INIT>: build A_0|0>, B, D, B
//                L_m:       A_{2m+1}, D, A_{2m+2}          (m=0..14)
//                H_m:       B, D, B                        (m=1..15)
//                L_15<FIN>: A_31, expectation -> out
// One state round-trip per step (half the traffic of a 2-pass scheme).
// The very last diagonal is dropped: it cannot change |psi|^2.
//
// Per-thread state: 64 amps (6 in-register qubits), only 2 cross-lane bits
// per kernel type; no LDS transposes at all.

#define DEV static __device__ __forceinline__

DEV float2 cmul(float2 a, float2 b){ return make_float2(a.x*b.x - a.y*b.y, a.x*b.y + a.y*b.x); }
DEV float2 cadd(float2 a, float2 b){ return make_float2(a.x+b.x, a.y+b.y); }
DEV float2 cscale(float s, float2 a){ return make_float2(s*a.x, s*a.y); }
DEV float2 cfma2(float2 u0, float2 a, float2 u1, float2 b){
  return make_float2(u0.x*a.x - u0.y*a.y + u1.x*b.x - u1.y*b.y,
                     u0.x*a.y + u0.y*a.x + u1.x*b.y + u1.y*b.x);
}
DEV void gpair(float2 &A, float2 &B, float2 u00, float2 u01, float2 u10, float2 u11){
  float2 na = cfma2(u00, A, u01, B);
  float2 nb = cfma2(u10, A, u11, B);
  A = na; B = nb;
}

// gate on an in-register bit (BIT = 1<<k of the in-thread amp index)
template<int BIT>
DEV void gate_in(float2* A, float2 u00, float2 u01, float2 u10, float2 u11){
  #pragma unroll
  for (int i=0;i<64;i++)
    if ((i & BIT) == 0) gpair(A[i], A[i|BIT], u00, u01, u10, u11);
}
// gate on a lane bit (xor mask M); hb side selected per lane
template<int M>
DEV void gate_xl(float2* A, int lane, float2 u00, float2 u01, float2 u10, float2 u11){
  const bool hb = (lane & M) != 0;
  float2 cA = hb ? u11 : u00;
  float2 cP = hb ? u10 : u01;
  #pragma unroll
  for (int i=0;i<64;i++){
    float2 p = make_float2(__shfl_xor(A[i].x, M, 64), __shfl_xor(A[i].y, M, 64));
    A[i] = cfma2(cA, A[i], cP, p);
  }
}

// ---------- setup: fused gates G_j, diagonal tables, out init ----------
__global__ __launch_bounds__(256) void k_setup(
    const float* __restrict__ w, const float* __restrict__ b_out,
    float* __restrict__ out, float2* __restrict__ G,
    float2* __restrict__ PHL, float2* __restrict__ PHB){
  int tid = threadIdx.x;
  if (tid < 16){
    int j = tid;
    float a0 = w[j*4+0], a1 = w[j*4+1], a2 = w[j*4+2];
    float c0 = cosf(0.5f*a0), s0 = sinf(0.5f*a0);
    float c1 = cosf(0.5f*a1), s1 = sinf(0.5f*a1);
    float c2 = cosf(0.5f*a2), s2 = sinf(0.5f*a2);
    float2 m00 = make_float2( c0*c1, -c0*s1);   // M = RZ(a1)*RX(a0)
    float2 m01 = make_float2(-s0*s1, -s0*c1);
    float2 m10 = make_float2( s0*s1, -s0*c1);
    float2 m11 = make_float2( c0*c1,  c0*s1);
    float2 mi2 = make_float2(0.f, -s2);
    G[j*4+0] = cadd(cscale(c2,m00), cmul(mi2,m10));   // G = RX(a2)*M
    G[j*4+1] = cadd(cscale(c2,m01), cmul(mi2,m11));
    G[j*4+2] = cadd(cmul(mi2,m00), cscale(c2,m10));
    G[j*4+3] = cadd(cmul(mi2,m01), cscale(c2,m11));
  }
  { // PHL[l]: chain edges (0,1)..(6,7), weight w[j+1,3]
    int l = tid; float phi = 0.f;
    for (int j=0;j<7;j++){
      float v = w[(j+1)*4+3];
      int u = ((l>>j)^(l>>(j+1)))&1;
      phi += -0.5f*v*(1.f-2.f*(float)u);
    }
    PHL[l] = make_float2(cosf(phi), sinf(phi));
  }
  // PHB[c][h]: edges (8,9)..(14,15) + cross (7,8)[w8] and (15,0)[w0];
  // c = bit0(l) | bit7(l)<<1
  for (int c=0;c<4;c++){
    int h = tid;
    float z0 = 1.f-2.f*(float)(c&1);
    float z7 = 1.f-2.f*(float)((c>>1)&1);
    float phi = 0.f;
    for (int k=0;k<7;k++){
      float v = w[(9+k)*4+3];
      int u = ((h>>k)^(h>>(k+1)))&1;
      phi += -0.5f*v*(1.f-2.f*(float)u);
    }
    phi += -0.5f*w[8*4+3]*z7*(1.f-2.f*(float)(h&1));
    phi += -0.5f*w[0*4+3]*(1.f-2.f*(float)((h>>7)&1))*z0;
    PHB[c*256+h] = make_float2(cosf(phi), sinf(phi));
  }
  out[tid] = b_out[0];
}

// ---------- TypeH: B, D, B  (high-qubit gates; h0..h5 in-thread, h6,h7 lane)
// lanes: bits0-3 = l0..l3, bits4,5 = h6,h7; waves: l4,l5; block: bb, lt = l6,l7.
template<bool INIT>
__global__ __launch_bounds__(256) void k_stepH(
    const float* __restrict__ x, const float2* __restrict__ G,
    const float2* __restrict__ PHL, const float2* __restrict__ PHB,
    float2* __restrict__ S, int b0){
  const int bb   = blockIdx.x >> 2;
  const int lt   = blockIdx.x & 3;
  const int lane = threadIdx.x & 63;
  const int wv   = threadIdx.x >> 6;
  const int l    = (lane & 15) + 16*wv + 64*lt;
  const int hhi  = lane >> 4;                 // h6,h7
  float2* base = S + (((size_t)bb) << 16) + l;
  float2 A[64];                               // amp i <-> h = i + 64*hhi
  if (INIT){
    float xv = x[(b0 + bb)*32 + 0];
    float cc = sqrtf(0.5f*(1.f+xv)), sn = sqrtf(0.5f*(1.f-xv));
    float2 P = make_float2(1.f, 0.f);         // P(l) = prod_j V_j(0)[bit_j(l)][0]
    #pragma unroll
    for (int j=0;j<8;j++){
      int bit = (l >> j) & 1;
      float2 g0 = G[j*4 + 2*bit + 0], g1 = G[j*4 + 2*bit + 1];
      P = cmul(P, cadd(cscale(cc, g0), cscale(sn, g1)));
    }
    #pragma unroll
    for (int i=0;i<64;i++) A[i] = make_float2(0.f, 0.f);
    if (hhi == 0) A[0] = P;                   // h==0 only
  } else {
    #pragma unroll
    for (int i=0;i<64;i++) A[i] = base[((size_t)i + 64*(size_t)hhi)*256];
  }
  const float2* Gh = G + 32;                  // gates for qubits 8..15
  #pragma unroll 1
  for (int rep=0; rep<2; rep++){
    gate_in<1> (A, Gh[0], Gh[1], Gh[2], Gh[3]);        // h0
    gate_in<2> (A, Gh[4], Gh[5], Gh[6], Gh[7]);        // h1
    gate_in<4> (A, Gh[8], Gh[9], Gh[10],Gh[11]);       // h2
    gate_in<8> (A, Gh[12],Gh[13],Gh[14],Gh[15]);       // h3
    gate_in<16>(A, Gh[16],Gh[17],Gh[18],Gh[19]);       // h4
    gate_in<32>(A, Gh[20],Gh[21],Gh[22],Gh[23]);       // h5
    gate_xl<16>(A, lane, Gh[24],Gh[25],Gh[26],Gh[27]); // h6 (lane bit4)
    gate_xl<32>(A, lane, Gh[28],Gh[29],Gh[30],Gh[31]); // h7 (lane bit5)
    if (rep == 0){                                     // diagonal D
      const int c = (l & 1) | (((l >> 7) & 1) << 1);
      const float2 phl = PHL[l];
      #pragma unroll
      for (int i=0;i<64;i++){
        float2 ph = PHB[c*256 + i + 64*hhi];
        A[i] = cmul(A[i], cmul(ph, phl));
      }
    }
  }
  #pragma unroll
  for (int i=0;i<64;i++) base[((size_t)i + 64*(size_t)hhi)*256] = A[i];
}

// ---------- TypeL: A_t, D, A_{t+1}  (low-qubit gates; l0,l6,l7,h0-2 in-thread)
// in-thread i bits: 0=l0, 1=l6, 2=l7, 3..5=h0..h2
// lanes: bits0-4 = l1..l5, bit5 = h5; waves: h3,h4; block: bb, ht = h6,h7.
template<bool FINAL>
__global__ __launch_bounds__(256) void k_stepL(
    const float* __restrict__ x, const float2* __restrict__ G,
    const float2* __restrict__ PHL, const float2* __restrict__ PHB,
    const float* __restrict__ w_out, float2* __restrict__ S,
    float* __restrict__ out, int t1, int b0){
  const int bb   = blockIdx.x >> 2;
  const int ht   = blockIdx.x & 3;
  const int lane = threadIdx.x & 63;
  const int wv   = threadIdx.x >> 6;
  const int lmid = (lane & 31) << 1;                   // l1..l5
  const int hbase = 8*wv + 32*(lane >> 5) + 64*ht;     // h3,h4 | h5 | h6,h7
  __shared__ float2 V[2][32];
  __shared__ float red[4];
  if (threadIdx.x < (FINAL ? 8 : 16)){
    int set = threadIdx.x >> 3, j = threadIdx.x & 7;
    float xv = x[(b0 + bb)*32 + t1 + set];
    float cc = sqrtf(0.5f*(1.f+xv));
    float sn = sqrtf(0.5f*(1.f-xv));
    float2 g00=G[j*4+0], g01=G[j*4+1], g10=G[j*4+2], g11=G[j*4+3];
    V[set][j*4+0] = cadd(cscale( cc,g00), cscale(sn,g01));   // V = G * Ry
    V[set][j*4+1] = cadd(cscale(-sn,g00), cscale(cc,g01));
    V[set][j*4+2] = cadd(cscale( cc,g10), cscale(sn,g11));
    V[set][j*4+3] = cadd(cscale(-sn,g10), cscale(cc,g11));
  }
  __syncthreads();
  float2* base = S + (((size_t)bb) << 16);
  float2 A[64];
  #pragma unroll
  for (int p=0;p<32;p++){                     // pair p: bits0,1=l6,l7; 2..4=h0..2
    int lh = p & 3, hl = p >> 2;
    float4 v = *(const float4*)(base + (size_t)(hbase + hl)*256 + lmid + 64*lh);
    A[2*p]   = make_float2(v.x, v.y);
    A[2*p+1] = make_float2(v.z, v.w);
  }
  #pragma unroll 1
  for (int rep=0; rep<(FINAL?1:2); rep++){
    const float2* Vp = &V[rep][0];
    gate_in<1> (A, Vp[0], Vp[1], Vp[2], Vp[3]);         // j=0 (l0)
    gate_xl<1> (A, lane, Vp[4], Vp[5], Vp[6], Vp[7]);   // j=1 (l1)
    gate_xl<2> (A, lane, Vp[8], Vp[9], Vp[10],Vp[11]);  // j=2
    gate_xl<4> (A, lane, Vp[12],Vp[13],Vp[14],Vp[15]);  // j=3
    gate_xl<8> (A, lane, Vp[16],Vp[17],Vp[18],Vp[19]);  // j=4
    gate_xl<16>(A, lane, Vp[20],Vp[21],Vp[22],Vp[23]);  // j=5
    gate_in<2> (A, Vp[24],Vp[25],Vp[26],Vp[27]);        // j=6 (l6)
    gate_in<4> (A, Vp[28],Vp[29],Vp[30],Vp[31]);        // j=7 (l7)
    if (!FINAL && rep == 0){                            // diagonal D
      #pragma unroll
      for (int hl=0; hl<8; hl++){
        const int h = hbase + hl;
        float2 phb0 = PHB[0*256+h], phb1 = PHB[1*256+h];
        float2 phb2 = PHB[2*256+h], phb3 = PHB[3*256+h];
        #pragma unroll
        for (int q=0;q<8;q++){                // q bits: 0=l0, 1=l6, 2=l7
          const int i = hl*8 + q;
          const int l = (q&1) + lmid + 64*((q>>1)&3);
          float2 phb = (q&1) ? (((q>>2)&1) ? phb3 : phb1)
                             : (((q>>2)&1) ? phb2 : phb0);
          A[i] = cmul(A[i], cmul(PHL[l], phb));
        }
      }
    }
  }
  if (FINAL){
    float w0 = w_out[0], w6 = w_out[6], w7 = w_out[7];
    float qlane = 0.f;
    #pragma unroll
    for (int j=1;j<6;j++) qlane += w_out[j] * (1.f - 2.f*(float)((lane>>(j-1))&1));
    float acc = 0.f;
    #pragma unroll
    for (int i=0;i<64;i++){
      float q = qlane + ((i&1) ? -w0 : w0) + (((i>>1)&1) ? -w6 : w6)
                      + (((i>>2)&1) ? -w7 : w7);
      acc += q * (A[i].x*A[i].x + A[i].y*A[i].y);
    }
    #pragma unroll
    for (int m=1;m<64;m<<=1) acc += __shfl_xor(acc, m, 64);
    if (lane == 0) red[wv] = acc;
    __syncthreads();
    if (threadIdx.x == 0) atomicAdd(out + b0 + bb, red[0]+red[1]+red[2]+red[3]);
  } else {
    #pragma unroll
    for (int p=0;p<32;p++){
      int lh = p & 3, hl = p >> 2;
      *(float4*)(base + (size_t)(hbase + hl)*256 + lmid + 64*lh) =
          make_float4(A[2*p].x, A[2*p].y, A[2*p+1].x, A[2*p+1].y);
    }
  }
}

extern "C" void kernel_launch(void* const* d_in, const int* in_sizes, int n_in,
                              void* d_out, int out_size, void* d_ws, size_t ws_size,
                              hipStream_t stream){
  const float* x     = (const float*)d_in[0];   // [256,32]
  const float* w     = (const float*)d_in[1];   // [16,4]
  const float* w_out = (const float*)d_in[2];   // [1,8]
  const float* b_out = (const float*)d_in[3];   // [1]
  float* out = (float*)d_out;                   // [256]

  const size_t S_BYTES = (size_t)128 * 65536 * sizeof(float2);  // 64 MB chunk
  const size_t NEED = S_BYTES + 512 + 2048 + 8192;
  if (ws_size < NEED) return;

  float2* S   = (float2*)d_ws;
  float2* G   = (float2*)((char*)d_ws + S_BYTES);  // 64 entries
  float2* PHL = G + 64;                            // 256 entries
  float2* PHB = PHL + 256;                         // 1024 entries

  k_setup<<<1,256,0,stream>>>(w, b_out, out, G, PHL, PHB);
  for (int c=0;c<2;c++){
    const int b0 = c*128;
    k_stepH<true><<<512,256,0,stream>>>(x, G, PHL, PHB, S, b0);
    for (int m=0;m<15;m++){
      k_stepL<false><<<512,256,0,stream>>>(x, G, PHL, PHB, w_out, S, out, 2*m+1, b0);
      k_stepH<false><<<512,256,0,stream>>>(x, G, PHL, PHB, S, b0);
    }
    k_stepL<true><<<512,256,0,stream>>>(x, G, PHL, PHB, w_out, S, out, 31, b0);
  }
}

// Round 6
// 5202.678 us; speedup vs baseline: 2.2908x; 2.2908x over previous
//
#include <hip/hip_runtime.h>
#include <hip/hip_bf16.h>
#include <math.h>

// QRNN quantum-circuit simulator, 16 qubits, B=256, T=32.
// State layout: float2 S[bb][s], s = h*256 + l; qubit j<8 <-> bit j of l,
// qubit 8+k <-> bit k of h. bb indexes the current 128-batch chunk (two
// independent chunks reuse the same 64MB workspace -> L3-resident).
//
// Schedule (verified round 2/3; gates on disjoint qubits commute, final
// diagonal dropped since output depends on |psi|^2 only):
//   H<INIT>: build (A_0 (x) B)|0> directly, D, B
//   L_m:     A_{2m+1}, D, A_{2m+2}     (m=0..14)
//   H:       B, D, B                   (between L's)
//   L<FIN>:  A_31, expectation -> out
// One state round-trip per timestep. Kernel internals use the round-1
// low-VGPR structures (4 amps/thread; stepH via LDS transpose) — the round-4
// 64-amp variant spilled (VGPR=256, scratch writes ~61MB/dispatch).

#define DEV static __device__ __forceinline__

DEV float2 cmul(float2 a, float2 b){ return make_float2(a.x*b.x - a.y*b.y, a.x*b.y + a.y*b.x); }
DEV float2 cadd(float2 a, float2 b){ return make_float2(a.x+b.x, a.y+b.y); }
DEV float2 cscale(float s, float2 a){ return make_float2(s*a.x, s*a.y); }
DEV float2 cfma2(float2 u0, float2 a, float2 u1, float2 b){
  return make_float2(u0.x*a.x - u0.y*a.y + u1.x*b.x - u1.y*b.y,
                     u0.x*a.y + u0.y*a.x + u1.x*b.y + u1.y*b.x);
}
DEV float2 shx(float2 v, int m){
  return make_float2(__shfl_xor(v.x, m, 64), __shfl_xor(v.y, m, 64));
}
DEV void gpair(float2 &A, float2 &B, float2 u00, float2 u01, float2 u10, float2 u11){
  float2 na = cfma2(u00, A, u01, B);
  float2 nb = cfma2(u10, A, u11, B);
  A = na; B = nb;
}

// Apply 8 single-qubit gates to a 256-amplitude slice held by one wave.
// Local index n: bit0 and bit7 in-thread, bits 1..6 = lane bits 0..5.
// a0: n=2L, a1: n=2L+1, a2: n=128+2L, a3: n=129+2L.
DEV void apply8(float2 &a0, float2 &a1, float2 &a2, float2 &a3, int lane,
                const float2* __restrict__ gm){
  gpair(a0,a1, gm[0],gm[1],gm[2],gm[3]);        // bit 0
  gpair(a2,a3, gm[0],gm[1],gm[2],gm[3]);
  #pragma unroll
  for (int k=1;k<=6;k++){                        // bits 1..6 cross-lane
    const int m = 1<<(k-1);
    const bool hb = (lane>>(k-1)) & 1;
    float2 u00=gm[4*k+0], u01=gm[4*k+1], u10=gm[4*k+2], u11=gm[4*k+3];
    float2 cA = hb? u11:u00;
    float2 cP = hb? u10:u01;
    a0 = cfma2(cA,a0,cP,shx(a0,m));
    a1 = cfma2(cA,a1,cP,shx(a1,m));
    a2 = cfma2(cA,a2,cP,shx(a2,m));
    a3 = cfma2(cA,a3,cP,shx(a3,m));
  }
  gpair(a0,a2, gm[28],gm[29],gm[30],gm[31]);    // bit 7
  gpair(a1,a3, gm[28],gm[29],gm[30],gm[31]);
}

// ---------- setup: fused gates G_j, diagonal tables, B|0> table, out init ----
__global__ __launch_bounds__(256) void k_setup(
    const float* __restrict__ w, const float* __restrict__ b_out,
    float* __restrict__ out, float2* __restrict__ G,
    float2* __restrict__ PHL, float2* __restrict__ PHB,
    float2* __restrict__ PH0){
  __shared__ float2 Gs[64];
  int tid = threadIdx.x;
  if (tid < 16){
    int j = tid;
    float a0 = w[j*4+0], a1 = w[j*4+1], a2 = w[j*4+2];
    float c0 = cosf(0.5f*a0), s0 = sinf(0.5f*a0);
    float c1 = cosf(0.5f*a1), s1 = sinf(0.5f*a1);
    float c2 = cosf(0.5f*a2), s2 = sinf(0.5f*a2);
    float2 m00 = make_float2( c0*c1, -c0*s1);   // M = RZ(a1)*RX(a0)
    float2 m01 = make_float2(-s0*s1, -s0*c1);
    float2 m10 = make_float2( s0*s1, -s0*c1);
    float2 m11 = make_float2( c0*c1,  c0*s1);
    float2 mi2 = make_float2(0.f, -s2);
    float2 g0 = cadd(cscale(c2,m00), cmul(mi2,m10));   // G = RX(a2)*M
    float2 g1 = cadd(cscale(c2,m01), cmul(mi2,m11));
    float2 g2 = cadd(cmul(mi2,m00), cscale(c2,m10));
    float2 g3 = cadd(cmul(mi2,m01), cscale(c2,m11));
    Gs[j*4+0]=g0; Gs[j*4+1]=g1; Gs[j*4+2]=g2; Gs[j*4+3]=g3;
    G[j*4+0]=g0;  G[j*4+1]=g1;  G[j*4+2]=g2;  G[j*4+3]=g3;
  }
  __syncthreads();
  { // PHL[l]: chain edges (0,1)..(6,7), weight w[j+1,3]
    int l = tid; float phi = 0.f;
    for (int j=0;j<7;j++){
      float v = w[(j+1)*4+3];
      int u = ((l>>j)^(l>>(j+1)))&1;
      phi += -0.5f*v*(1.f-2.f*(float)u);
    }
    PHL[l] = make_float2(cosf(phi), sinf(phi));
  }
  // PHB[c][h]: edges (8,9)..(14,15) + cross (7,8)[w8] and (15,0)[w0];
  // c = bit0(l) | bit7(l)<<1
  for (int c=0;c<4;c++){
    int h = tid;
    float z0 = 1.f-2.f*(float)(c&1);
    float z7 = 1.f-2.f*(float)((c>>1)&1);
    float phi = 0.f;
    for (int k=0;k<7;k++){
      float v = w[(9+k)*4+3];
      int u = ((h>>k)^(h>>(k+1)))&1;
      phi += -0.5f*v*(1.f-2.f*(float)u);
    }
    phi += -0.5f*w[8*4+3]*z7*(1.f-2.f*(float)(h&1));
    phi += -0.5f*w[0*4+3]*(1.f-2.f*(float)((h>>7)&1))*z0;
    PHB[c*256+h] = make_float2(cosf(phi), sinf(phi));
  }
  { // PH0[h] = amplitude of B|0>_high at h = prod_k Gh_k[bit_k(h)][0]
    float2 p = make_float2(1.f, 0.f);
    #pragma unroll
    for (int k=0;k<8;k++) p = cmul(p, Gs[(8+k)*4 + 2*((tid>>k)&1)]);
    PH0[tid] = p;
  }
  out[tid] = b_out[0];
}

// ---------- TypeL: A_t1, D, A_{t1+1} on low qubits (registers + shfl) -------
// grid = 128 bb * 16 tiles; 4 waves/block, 4 h-blocks per wave.
template<bool FINAL>
__global__ __launch_bounds__(256) void k_stepL(
    const float* __restrict__ x, const float2* __restrict__ G,
    const float2* __restrict__ PHL, const float2* __restrict__ PHB,
    const float* __restrict__ w_out, float2* __restrict__ S,
    float* __restrict__ out, int t1, int b0){
  const int bb   = blockIdx.x >> 4;
  const int tile = blockIdx.x & 15;
  const int lane = threadIdx.x & 63;
  const int wv   = threadIdx.x >> 6;
  __shared__ float2 V[2][32];                  // fused V_j = G_j * Ry(x_t)
  __shared__ float red[4];
  if (threadIdx.x < (FINAL ? 8 : 16)){
    int set = threadIdx.x >> 3, j = threadIdx.x & 7;
    float xv = x[(b0 + bb)*32 + t1 + set];
    float cc = sqrtf(0.5f*(1.f+xv));           // cos(arccos(x)/2)
    float sn = sqrtf(0.5f*(1.f-xv));
    float2 g00=G[j*4+0], g01=G[j*4+1], g10=G[j*4+2], g11=G[j*4+3];
    V[set][j*4+0] = cadd(cscale( cc,g00), cscale(sn,g01));
    V[set][j*4+1] = cadd(cscale(-sn,g00), cscale(cc,g01));
    V[set][j*4+2] = cadd(cscale( cc,g10), cscale(sn,g11));
    V[set][j*4+3] = cadd(cscale(-sn,g10), cscale(cc,g11));
  }
  __syncthreads();
  float acc = 0.f;
  #pragma unroll 1
  for (int it=0; it<4; ++it){
    const int hb = tile*16 + wv*4 + it;
    float2* blk = S + (((size_t)bb)<<16) + (size_t)hb*256;
    const float4* p4 = (const float4*)blk;
    float4 lo = p4[lane];
    float4 hi = p4[64+lane];
    float2 a0 = make_float2(lo.x,lo.y), a1 = make_float2(lo.z,lo.w);
    float2 a2 = make_float2(hi.x,hi.y), a3 = make_float2(hi.z,hi.w);
    apply8(a0,a1,a2,a3,lane, &V[0][0]);        // A_t1
    if (!FINAL){
      // diagonal D: amps a0..a3 have (l0,l7) = (0,0),(1,0),(0,1),(1,1) -> c=0..3
      float2 s0 = PHB[0*256+hb], s1 = PHB[1*256+hb];
      float2 s2 = PHB[2*256+hb], s3 = PHB[3*256+hb];   // wave-uniform
      const float4* q4 = (const float4*)PHL;
      float4 plo = q4[lane];                   // PHL[2L], PHL[2L+1]
      float4 phi = q4[64+lane];                // PHL[128+2L], PHL[129+2L]
      a0 = cmul(a0, cmul(make_float2(plo.x,plo.y), s0));
      a1 = cmul(a1, cmul(make_float2(plo.z,plo.w), s1));
      a2 = cmul(a2, cmul(make_float2(phi.x,phi.y), s2));
      a3 = cmul(a3, cmul(make_float2(phi.z,phi.w), s3));
      apply8(a0,a1,a2,a3,lane, &V[1][0]);      // A_{t1+1}
      float4* o4 = (float4*)blk;
      o4[lane]    = make_float4(a0.x,a0.y,a1.x,a1.y);
      o4[64+lane] = make_float4(a2.x,a2.y,a3.x,a3.y);
    } else {
      // expectation: Q(l) = sum_j w_out[j]*(1-2 bit_j(l)); data qubits = l bits
      float w0 = w_out[0], w7 = w_out[7];
      float qlane = 0.f;
      #pragma unroll
      for (int j=1;j<7;j++) qlane += w_out[j] * (1.f - 2.f*(float)((lane>>(j-1))&1));
      acc += (qlane + w0 + w7) * (a0.x*a0.x + a0.y*a0.y);
      acc += (qlane - w0 + w7) * (a1.x*a1.x + a1.y*a1.y);
      acc += (qlane + w0 - w7) * (a2.x*a2.x + a2.y*a2.y);
      acc += (qlane - w0 - w7) * (a3.x*a3.x + a3.y*a3.y);
    }
  }
  if (FINAL){
    #pragma unroll
    for (int m=1;m<64;m<<=1) acc += __shfl_xor(acc, m, 64);
    if (lane == 0) red[wv] = acc;
    __syncthreads();
    if (threadIdx.x == 0) atomicAdd(out + b0 + bb, red[0]+red[1]+red[2]+red[3]);
  }
}

// ---------- TypeH: B, D, B on high qubits (LDS transpose) -------------------
// grid = 128 bb * 16 l-tiles (16 l each); float4 128B segments both ways.
// INIT: build (A_0 (x) B)|0> = Plow(l)*PH0[h] directly, then D, then B.
template<bool INIT>
__global__ __launch_bounds__(256) void k_stepH(
    const float* __restrict__ x, const float2* __restrict__ G,
    const float2* __restrict__ PHL, const float2* __restrict__ PHB,
    const float2* __restrict__ PH0, float2* __restrict__ S, int b0){
  const int bb = blockIdx.x >> 4;
  const int lt = blockIdx.x & 15;
  const int l0 = lt*16;
  const int tid  = threadIdx.x;
  const int lane = tid & 63;
  const int wv   = tid >> 6;
  __shared__ float2 lds[16*258];   // column dl at [dl*258 .. dl*258+256)
  __shared__ float2 V[32];         // INIT only: A_0 gates (column 0 entries)
  float4* Sb4 = (float4*)(S + (((size_t)bb)<<16));
  const int colbase = l0 >> 1;
  if (INIT){
    if (tid < 8){
      int j = tid;
      float xv = x[(b0 + bb)*32 + 0];
      float cc = sqrtf(0.5f*(1.f+xv));
      float sn = sqrtf(0.5f*(1.f-xv));
      float2 g00=G[j*4+0], g01=G[j*4+1], g10=G[j*4+2], g11=G[j*4+3];
      V[j*4+0] = cadd(cscale(cc,g00), cscale(sn,g01));   // V[bit=0][0]
      V[j*4+2] = cadd(cscale(cc,g10), cscale(sn,g11));   // V[bit=1][0]
    }
    __syncthreads();
  } else {
    #pragma unroll
    for (int k=0;k<8;k++){         // stage in: 128B segments
      int idx = k*256 + tid;
      int q = idx & 7, h = idx >> 3;
      float4 v = Sb4[h*128 + colbase + q];
      int dl2 = q*2;
      lds[dl2*258 + h]     = make_float2(v.x, v.y);
      lds[(dl2+1)*258 + h] = make_float2(v.z, v.w);
    }
    __syncthreads();
  }
  #pragma unroll 1
  for (int cc=0;cc<4;cc++){        // each wave owns 4 columns
    const int dl = wv*4 + cc;
    const int l = l0 + dl;
    float2* col = lds + dl*258;
    float2 a0,a1,a2,a3;
    if (INIT){
      float2 Pl = make_float2(1.f, 0.f);       // A_0|0> amplitude at l
      #pragma unroll
      for (int j=0;j<8;j++) Pl = cmul(Pl, V[j*4 + 2*((l>>j)&1)]);
      const float4* z4 = (const float4*)PH0;
      float4 zlo = z4[lane];
      float4 zhi = z4[64+lane];
      a0 = cmul(Pl, make_float2(zlo.x,zlo.y));
      a1 = cmul(Pl, make_float2(zlo.z,zlo.w));
      a2 = cmul(Pl, make_float2(zhi.x,zhi.y));
      a3 = cmul(Pl, make_float2(zhi.z,zhi.w));
    } else {
      float4 lo = *(const float4*)(col + 2*lane);
      float4 hi = *(const float4*)(col + 128 + 2*lane);
      a0 = make_float2(lo.x,lo.y); a1 = make_float2(lo.z,lo.w);
      a2 = make_float2(hi.x,hi.y); a3 = make_float2(hi.z,hi.w);
      apply8(a0,a1,a2,a3,lane, G + 32);        // first B
    }
    { // diagonal D: phl uniform per column; PHB per amp (h = 2L..)
      const int c = (l & 1) | (((l >> 7) & 1) << 1);
      const float2 phl = PHL[l];
      const float4* r4 = (const float4*)(PHB + c*256);
      float4 plo = r4[lane];
      float4 phi = r4[64+lane];
      a0 = cmul(a0, cmul(phl, make_float2(plo.x, plo.y)));
      a1 = cmul(a1, cmul(phl, make_float2(plo.z, plo.w)));
      a2 = cmul(a2, cmul(phl, make_float2(phi.x, phi.y)));
      a3 = cmul(a3, cmul(phl, make_float2(phi.z, phi.w)));
    }
    apply8(a0,a1,a2,a3,lane, G + 32);          // second B
    *(float4*)(col + 2*lane)       = make_float4(a0.x,a0.y,a1.x,a1.y);
    *(float4*)(col + 128 + 2*lane) = make_float4(a2.x,a2.y,a3.x,a3.y);
  }
  __syncthreads();
  #pragma unroll
  for (int k=0;k<8;k++){           // stage out: mirror of stage in
    int idx = k*256 + tid;
    int q = idx & 7, h = idx >> 3;
    int dl2 = q*2;
    float2 v0 = lds[dl2*258 + h];
    float2 v1 = lds[(dl2+1)*258 + h];
    Sb4[h*128 + colbase + q] = make_float4(v0.x, v0.y, v1.x, v1.y);
  }
}

extern "C" void kernel_launch(void* const* d_in, const int* in_sizes, int n_in,
                              void* d_out, int out_size, void* d_ws, size_t ws_size,
                              hipStream_t stream){
  const float* x     = (const float*)d_in[0];   // [256,32]
  const float* w     = (const float*)d_in[1];   // [16,4]
  const float* w_out = (const float*)d_in[2];   // [1,8]
  const float* b_out = (const float*)d_in[3];   // [1]
  float* out = (float*)d_out;                   // [256]

  const size_t S_BYTES = (size_t)128 * 65536 * sizeof(float2);  // 64 MB chunk
  const size_t NEED = S_BYTES + (64+256+1024+256)*sizeof(float2);
  if (ws_size < NEED) return;

  float2* S   = (float2*)d_ws;
  float2* G   = (float2*)((char*)d_ws + S_BYTES);  // 64 entries
  float2* PHL = G + 64;                            // 256 entries
  float2* PHB = PHL + 256;                         // 1024 entries
  float2* PH0 = PHB + 1024;                        // 256 entries

  k_setup<<<1,256,0,stream>>>(w, b_out, out, G, PHL, PHB, PH0);
  for (int c=0;c<2;c++){
    const int b0 = c*128;
    k_stepH<true><<<2048,256,0,stream>>>(x, G, PHL, PHB, PH0, S, b0);
    for (int m=0;m<15;m++){
      k_stepL<false><<<2048,256,0,stream>>>(x, G, PHL, PHB, w_out, S, out, 2*m+1, b0);
      k_stepH<false><<<2048,256,0,stream>>>(x, G, PHL, PHB, PH0, S, b0);
    }
    k_stepL<true><<<2048,256,0,stream>>>(x, G, PHL, PHB, w_out, S, out, 31, b0);
  }
}

// Round 8
// 3646.587 us; speedup vs baseline: 3.2683x; 1.4267x over previous
//
#include <hip/hip_runtime.h>
#include <hip/hip_bf16.h>
#include <math.h>

// QRNN quantum-circuit simulator, 16 qubits, B=256, T=32.
// State layout: float2 S[bb][s], s = h*256 + l; qubit j<8 <-> bit j of l,
// qubit 8+k <-> bit k of h. bb indexes the current 128-batch chunk (two
// independent chunks reuse the same 64MB workspace -> L3-resident).
//
// Schedule (verified r2/r6):
//   H<INIT>: build (A_0 (x) B)|0> directly, D, B
//   L_m:     A_{2m+1}, D, A_{2m+2}     (m=0..14)
//   H:       B, D, B                   (between L's)
//   L<FIN>:  A_31, expectation -> out
// One state round-trip per timestep; final diagonal dropped (|psi|^2 output).
//
// r6 lesson: stepL hoisted BOTH V gate sets (128 VGPR) -> VGPR=132 -> 2
// waves/SIMD (m69 tier) -> 135us latency-bound. Fix: runtime-bounded rep
// loop (one V set live), launch_bounds(256,4) pinning the <=128-VGPR tier,
// and 8 amps/iter (two interleaved shfl chains) for in-wave ILP.

#define DEV static __device__ __forceinline__

DEV float2 cmul(float2 a, float2 b){ return make_float2(a.x*b.x - a.y*b.y, a.x*b.y + a.y*b.x); }
DEV float2 cadd(float2 a, float2 b){ return make_float2(a.x+b.x, a.y+b.y); }
DEV float2 cscale(float s, float2 a){ return make_float2(s*a.x, s*a.y); }
DEV float2 cfma2(float2 u0, float2 a, float2 u1, float2 b){
  return make_float2(u0.x*a.x - u0.y*a.y + u1.x*b.x - u1.y*b.y,
                     u0.x*a.y + u0.y*a.x + u1.x*b.y + u1.y*b.x);
}
DEV float2 shx(float2 v, int m){
  return make_float2(__shfl_xor(v.x, m, 64), __shfl_xor(v.y, m, 64));
}
DEV void gpair(float2 &A, float2 &B, float2 u00, float2 u01, float2 u10, float2 u11){
  float2 na = cfma2(u00, A, u01, B);
  float2 nb = cfma2(u10, A, u11, B);
  A = na; B = nb;
}

// Apply 8 single-qubit gates to one 256-amp slice (4 amps: a0..a3).
// Local index n: bit0,bit7 in-thread; bits 1..6 = lane bits 0..5.
// a0: n=2L, a1: n=2L+1, a2: n=128+2L, a3: n=129+2L.
DEV void apply8(float2 &a0, float2 &a1, float2 &a2, float2 &a3, int lane,
                const float2* __restrict__ gm){
  gpair(a0,a1, gm[0],gm[1],gm[2],gm[3]);
  gpair(a2,a3, gm[0],gm[1],gm[2],gm[3]);
  #pragma unroll
  for (int k=1;k<=6;k++){
    const int m = 1<<(k-1);
    const bool hb = (lane>>(k-1)) & 1;
    float2 u00=gm[4*k+0], u01=gm[4*k+1], u10=gm[4*k+2], u11=gm[4*k+3];
    float2 cA = hb? u11:u00;
    float2 cP = hb? u10:u01;
    a0 = cfma2(cA,a0,cP,shx(a0,m));
    a1 = cfma2(cA,a1,cP,shx(a1,m));
    a2 = cfma2(cA,a2,cP,shx(a2,m));
    a3 = cfma2(cA,a3,cP,shx(a3,m));
  }
  gpair(a0,a2, gm[28],gm[29],gm[30],gm[31]);
  gpair(a1,a3, gm[28],gm[29],gm[30],gm[31]);
}

// Two 256-amp slices (8 amps), stages interleaved for DS-latency hiding.
DEV void apply8_2(float2 &a0, float2 &a1, float2 &a2, float2 &a3,
                  float2 &b0, float2 &b1, float2 &b2, float2 &b3,
                  int lane, const float2* __restrict__ gm){
  gpair(a0,a1, gm[0],gm[1],gm[2],gm[3]);
  gpair(a2,a3, gm[0],gm[1],gm[2],gm[3]);
  gpair(b0,b1, gm[0],gm[1],gm[2],gm[3]);
  gpair(b2,b3, gm[0],gm[1],gm[2],gm[3]);
  #pragma unroll
  for (int k=1;k<=6;k++){
    const int m = 1<<(k-1);
    const bool hb = (lane>>(k-1)) & 1;
    float2 u00=gm[4*k+0], u01=gm[4*k+1], u10=gm[4*k+2], u11=gm[4*k+3];
    float2 cA = hb? u11:u00;
    float2 cP = hb? u10:u01;
    a0 = cfma2(cA,a0,cP,shx(a0,m));
    a1 = cfma2(cA,a1,cP,shx(a1,m));
    a2 = cfma2(cA,a2,cP,shx(a2,m));
    a3 = cfma2(cA,a3,cP,shx(a3,m));
    b0 = cfma2(cA,b0,cP,shx(b0,m));
    b1 = cfma2(cA,b1,cP,shx(b1,m));
    b2 = cfma2(cA,b2,cP,shx(b2,m));
    b3 = cfma2(cA,b3,cP,shx(b3,m));
  }
  gpair(a0,a2, gm[28],gm[29],gm[30],gm[31]);
  gpair(a1,a3, gm[28],gm[29],gm[30],gm[31]);
  gpair(b0,b2, gm[28],gm[29],gm[30],gm[31]);
  gpair(b1,b3, gm[28],gm[29],gm[30],gm[31]);
}

// ---------- setup: fused gates G_j, diagonal tables, B|0> table, out init ----
__global__ __launch_bounds__(256) void k_setup(
    const float* __restrict__ w, const float* __restrict__ b_out,
    float* __restrict__ out, float2* __restrict__ G,
    float2* __restrict__ PHL, float2* __restrict__ PHB,
    float2* __restrict__ PH0){
  __shared__ float2 Gs[64];
  int tid = threadIdx.x;
  if (tid < 16){
    int j = tid;
    float a0 = w[j*4+0], a1 = w[j*4+1], a2 = w[j*4+2];
    float c0 = cosf(0.5f*a0), s0 = sinf(0.5f*a0);
    float c1 = cosf(0.5f*a1), s1 = sinf(0.5f*a1);
    float c2 = cosf(0.5f*a2), s2 = sinf(0.5f*a2);
    float2 m00 = make_float2( c0*c1, -c0*s1);   // M = RZ(a1)*RX(a0)
    float2 m01 = make_float2(-s0*s1, -s0*c1);
    float2 m10 = make_float2( s0*s1, -s0*c1);
    float2 m11 = make_float2( c0*c1,  c0*s1);
    float2 mi2 = make_float2(0.f, -s2);
    float2 g0 = cadd(cscale(c2,m00), cmul(mi2,m10));   // G = RX(a2)*M
    float2 g1 = cadd(cscale(c2,m01), cmul(mi2,m11));
    float2 g2 = cadd(cmul(mi2,m00), cscale(c2,m10));
    float2 g3 = cadd(cmul(mi2,m01), cscale(c2,m11));
    Gs[j*4+0]=g0; Gs[j*4+1]=g1; Gs[j*4+2]=g2; Gs[j*4+3]=g3;
    G[j*4+0]=g0;  G[j*4+1]=g1;  G[j*4+2]=g2;  G[j*4+3]=g3;
  }
  __syncthreads();
  { // PHL[l]: chain edges (0,1)..(6,7), weight w[j+1,3]
    int l = tid; float phi = 0.f;
    for (int j=0;j<7;j++){
      float v = w[(j+1)*4+3];
      int u = ((l>>j)^(l>>(j+1)))&1;
      phi += -0.5f*v*(1.f-2.f*(float)u);
    }
    PHL[l] = make_float2(cosf(phi), sinf(phi));
  }
  // PHB[c][h]: edges (8,9)..(14,15) + cross (7,8)[w8] and (15,0)[w0];
  // c = bit0(l) | bit7(l)<<1
  for (int c=0;c<4;c++){
    int h = tid;
    float z0 = 1.f-2.f*(float)(c&1);
    float z7 = 1.f-2.f*(float)((c>>1)&1);
    float phi = 0.f;
    for (int k=0;k<7;k++){
      float v = w[(9+k)*4+3];
      int u = ((h>>k)^(h>>(k+1)))&1;
      phi += -0.5f*v*(1.f-2.f*(float)u);
    }
    phi += -0.5f*w[8*4+3]*z7*(1.f-2.f*(float)(h&1));
    phi += -0.5f*w[0*4+3]*(1.f-2.f*(float)((h>>7)&1))*z0;
    PHB[c*256+h] = make_float2(cosf(phi), sinf(phi));
  }
  { // PH0[h] = amplitude of B|0>_high at h
    float2 p = make_float2(1.f, 0.f);
    #pragma unroll
    for (int k=0;k<8;k++) p = cmul(p, Gs[(8+k)*4 + 2*((tid>>k)&1)]);
    PH0[tid] = p;
  }
  out[tid] = b_out[0];
}

// ---------- TypeL: A_t1 [, D, A_{t1+1}] on low qubits (registers + shfl) ----
// grid = 128 bb * 16 tiles; 4 waves/block; 2 iters * 2 h-blocks (8 amps).
// nrep runtime (mid=2, FINAL=1) -> rep loop can't unroll -> one V set live.
template<bool FINAL>
__global__ __launch_bounds__(256, 4) void k_stepL(
    const float* __restrict__ x, const float2* __restrict__ G,
    const float2* __restrict__ PHL, const float2* __restrict__ PHB,
    const float* __restrict__ w_out, float2* __restrict__ S,
    float* __restrict__ out, int t1, int b0, int nrep){
  const int bb   = blockIdx.x >> 4;
  const int tile = blockIdx.x & 15;
  const int lane = threadIdx.x & 63;
  const int wv   = threadIdx.x >> 6;
  __shared__ float2 V[2][32];                  // fused V_j = G_j * Ry(x_t)
  __shared__ float red[4];
  if (threadIdx.x < (FINAL ? 8 : 16)){
    int set = threadIdx.x >> 3, j = threadIdx.x & 7;
    float xv = x[(b0 + bb)*32 + t1 + set];
    float cc = sqrtf(0.5f*(1.f+xv));           // cos(arccos(x)/2)
    float sn = sqrtf(0.5f*(1.f-xv));
    float2 g00=G[j*4+0], g01=G[j*4+1], g10=G[j*4+2], g11=G[j*4+3];
    V[set][j*4+0] = cadd(cscale( cc,g00), cscale(sn,g01));
    V[set][j*4+1] = cadd(cscale(-sn,g00), cscale(cc,g01));
    V[set][j*4+2] = cadd(cscale( cc,g10), cscale(sn,g11));
    V[set][j*4+3] = cadd(cscale(-sn,g10), cscale(cc,g11));
  }
  __syncthreads();
  float acc = 0.f;
  #pragma unroll 1
  for (int it=0; it<2; ++it){
    const int hb = tile*16 + wv*4 + it*2;      // two consecutive h-blocks
    float2* blk = S + (((size_t)bb)<<16) + (size_t)hb*256;
    const float4* p4 = (const float4*)blk;
    float4 lo  = p4[lane];
    float4 hi  = p4[64+lane];
    float4 lo2 = p4[128+lane];
    float4 hi2 = p4[192+lane];
    float2 a0 = make_float2(lo.x,lo.y),  a1 = make_float2(lo.z,lo.w);
    float2 a2 = make_float2(hi.x,hi.y),  a3 = make_float2(hi.z,hi.w);
    float2 b0q= make_float2(lo2.x,lo2.y),b1 = make_float2(lo2.z,lo2.w);
    float2 b2 = make_float2(hi2.x,hi2.y),b3 = make_float2(hi2.z,hi2.w);
    #pragma unroll 1
    for (int rep=0; rep<nrep; ++rep){
      apply8_2(a0,a1,a2,a3, b0q,b1,b2,b3, lane, &V[rep][0]);
      if (!FINAL && rep==0){
        // diagonal D: amps 0..3 carry (l0,l7)=(0,0),(1,0),(0,1),(1,1) -> c=0..3
        float2 sA0=PHB[0*256+hb],   sA1=PHB[1*256+hb];
        float2 sA2=PHB[2*256+hb],   sA3=PHB[3*256+hb];     // wave-uniform
        float2 sB0=PHB[0*256+hb+1], sB1=PHB[1*256+hb+1];
        float2 sB2=PHB[2*256+hb+1], sB3=PHB[3*256+hb+1];
        const float4* q4 = (const float4*)PHL;
        float4 plo = q4[lane];                 // PHL[2L], PHL[2L+1]
        float4 phi = q4[64+lane];              // PHL[128+2L], PHL[129+2L]
        float2 pl0 = make_float2(plo.x,plo.y), pl1 = make_float2(plo.z,plo.w);
        float2 ph2 = make_float2(phi.x,phi.y), ph3 = make_float2(phi.z,phi.w);
        a0 = cmul(a0, cmul(pl0, sA0));
        a1 = cmul(a1, cmul(pl1, sA1));
        a2 = cmul(a2, cmul(ph2, sA2));
        a3 = cmul(a3, cmul(ph3, sA3));
        b0q= cmul(b0q,cmul(pl0, sB0));
        b1 = cmul(b1, cmul(pl1, sB1));
        b2 = cmul(b2, cmul(ph2, sB2));
        b3 = cmul(b3, cmul(ph3, sB3));
      }
    }
    if (!FINAL){
      float4* o4 = (float4*)blk;
      o4[lane]     = make_float4(a0.x,a0.y,a1.x,a1.y);
      o4[64+lane]  = make_float4(a2.x,a2.y,a3.x,a3.y);
      o4[128+lane] = make_float4(b0q.x,b0q.y,b1.x,b1.y);
      o4[192+lane] = make_float4(b2.x,b2.y,b3.x,b3.y);
    } else {
      // expectation: Q(l) = sum_j w_out[j]*(1-2 bit_j(l)); data qubits = l bits
      float w0 = w_out[0], w7 = w_out[7];
      float qlane = 0.f;
      #pragma unroll
      for (int j=1;j<7;j++) qlane += w_out[j] * (1.f - 2.f*(float)((lane>>(j-1))&1));
      acc += (qlane + w0 + w7) * (a0.x*a0.x + a0.y*a0.y);
      acc += (qlane - w0 + w7) * (a1.x*a1.x + a1.y*a1.y);
      acc += (qlane + w0 - w7) * (a2.x*a2.x + a2.y*a2.y);
      acc += (qlane - w0 - w7) * (a3.x*a3.x + a3.y*a3.y);
      acc += (qlane + w0 + w7) * (b0q.x*b0q.x + b0q.y*b0q.y);
      acc += (qlane - w0 + w7) * (b1.x*b1.x + b1.y*b1.y);
      acc += (qlane + w0 - w7) * (b2.x*b2.x + b2.y*b2.y);
      acc += (qlane - w0 - w7) * (b3.x*b3.x + b3.y*b3.y);
    }
  }
  if (FINAL){
    #pragma unroll
    for (int m=1;m<64;m<<=1) acc += __shfl_xor(acc, m, 64);
    if (lane == 0) red[wv] = acc;
    __syncthreads();
    if (threadIdx.x == 0) atomicAdd(out + b0 + bb, red[0]+red[1]+red[2]+red[3]);
  }
}

// ---------- TypeH: B, D, B on high qubits (LDS transpose) -------------------
// grid = 128 bb * 16 l-tiles (16 l each); float4 128B segments both ways.
// INIT: build (A_0 (x) B)|0> = Plow(l)*PH0[h] directly, then D, then B.
template<bool INIT>
__global__ __launch_bounds__(256) void k_stepH(
    const float* __restrict__ x, const float2* __restrict__ G,
    const float2* __restrict__ PHL, const float2* __restrict__ PHB,
    const float2* __restrict__ PH0, float2* __restrict__ S, int b0){
  const int bb = blockIdx.x >> 4;
  const int lt = blockIdx.x & 15;
  const int l0 = lt*16;
  const int tid  = threadIdx.x;
  const int lane = tid & 63;
  const int wv   = tid >> 6;
  __shared__ float2 lds[16*258];   // column dl at [dl*258 .. dl*258+256)
  __shared__ float2 V[32];         // INIT only: A_0 gates (column 0 entries)
  float4* Sb4 = (float4*)(S + (((size_t)bb)<<16));
  const int colbase = l0 >> 1;
  if (INIT){
    if (tid < 8){
      int j = tid;
      float xv = x[(b0 + bb)*32 + 0];
      float cc = sqrtf(0.5f*(1.f+xv));
      float sn = sqrtf(0.5f*(1.f-xv));
      float2 g00=G[j*4+0], g01=G[j*4+1], g10=G[j*4+2], g11=G[j*4+3];
      V[j*4+0] = cadd(cscale(cc,g00), cscale(sn,g01));   // V[bit=0][0]
      V[j*4+2] = cadd(cscale(cc,g10), cscale(sn,g11));   // V[bit=1][0]
    }
    __syncthreads();
  } else {
    #pragma unroll
    for (int k=0;k<8;k++){         // stage in: 128B segments
      int idx = k*256 + tid;
      int q = idx & 7, h = idx >> 3;
      float4 v = Sb4[h*128 + colbase + q];
      int dl2 = q*2;
      lds[dl2*258 + h]     = make_float2(v.x, v.y);
      lds[(dl2+1)*258 + h] = make_float2(v.z, v.w);
    }
    __syncthreads();
  }
  #pragma unroll 1
  for (int cc=0;cc<4;cc++){        // each wave owns 4 columns
    const int dl = wv*4 + cc;
    const int l = l0 + dl;
    float2* col = lds + dl*258;
    float2 a0,a1,a2,a3;
    if (INIT){
      float2 Pl = make_float2(1.f, 0.f);       // A_0|0> amplitude at l
      #pragma unroll
      for (int j=0;j<8;j++) Pl = cmul(Pl, V[j*4 + 2*((l>>j)&1)]);
      const float4* z4 = (const float4*)PH0;
      float4 zlo = z4[lane];
      float4 zhi = z4[64+lane];
      a0 = cmul(Pl, make_float2(zlo.x,zlo.y));
      a1 = cmul(Pl, make_float2(zlo.z,zlo.w));
      a2 = cmul(Pl, make_float2(zhi.x,zhi.y));
      a3 = cmul(Pl, make_float2(zhi.z,zhi.w));
    } else {
      float4 lo = *(const float4*)(col + 2*lane);
      float4 hi = *(const float4*)(col + 128 + 2*lane);
      a0 = make_float2(lo.x,lo.y); a1 = make_float2(lo.z,lo.w);
      a2 = make_float2(hi.x,hi.y); a3 = make_float2(hi.z,hi.w);
      apply8(a0,a1,a2,a3,lane, G + 32);        // first B
    }
    { // diagonal D: phl uniform per column; PHB per amp (h = 2L..)
      const int c = (l & 1) | (((l >> 7) & 1) << 1);
      const float2 phl = PHL[l];
      const float4* r4 = (const float4*)(PHB + c*256);
      float4 plo = r4[lane];
      float4 phi = r4[64+lane];
      a0 = cmul(a0, cmul(phl, make_float2(plo.x, plo.y)));
      a1 = cmul(a1, cmul(phl, make_float2(plo.z, plo.w)));
      a2 = cmul(a2, cmul(phl, make_float2(phi.x, phi.y)));
      a3 = cmul(a3, cmul(phl, make_float2(phi.z, phi.w)));
    }
    apply8(a0,a1,a2,a3,lane, G + 32);          // second B
    *(float4*)(col + 2*lane)       = make_float4(a0.x,a0.y,a1.x,a1.y);
    *(float4*)(col + 128 + 2*lane) = make_float4(a2.x,a2.y,a3.x,a3.y);
  }
  __syncthreads();
  #pragma unroll
  for (int k=0;k<8;k++){           // stage out: mirror of stage in
    int idx = k*256 + tid;
    int q = idx & 7, h = idx >> 3;
    int dl2 = q*2;
    float2 v0 = lds[dl2*258 + h];
    float2 v1 = lds[(dl2+1)*258 + h];
    Sb4[h*128 + colbase + q] = make_float4(v0.x, v0.y, v1.x, v1.y);
  }
}

extern "C" void kernel_launch(void* const* d_in, const int* in_sizes, int n_in,
                              void* d_out, int out_size, void* d_ws, size_t ws_size,
                              hipStream_t stream){
  const float* x     = (const float*)d_in[0];   // [256,32]
  const float* w     = (const float*)d_in[1];   // [16,4]
  const float* w_out = (const float*)d_in[2];   // [1,8]
  const float* b_out = (const float*)d_in[3];   // [1]
  float* out = (float*)d_out;                   // [256]

  const size_t S_BYTES = (size_t)128 * 65536 * sizeof(float2);  // 64 MB chunk
  const size_t NEED = S_BYTES + (64+256+1024+256)*sizeof(float2);
  if (ws_size < NEED) return;

  float2* S   = (float2*)d_ws;
  float2* G   = (float2*)((char*)d_ws + S_BYTES);  // 64 entries
  float2* PHL = G + 64;                            // 256 entries
  float2* PHB = PHL + 256;                         // 1024 entries
  float2* PH0 = PHB + 1024;                        // 256 entries

  k_setup<<<1,256,0,stream>>>(w, b_out, out, G, PHL, PHB, PH0);
  for (int c=0;c<2;c++){
    const int b0 = c*128;
    k_stepH<true><<<2048,256,0,stream>>>(x, G, PHL, PHB, PH0, S, b0);
    for (int m=0;m<15;m++){
      k_stepL<false><<<2048,256,0,stream>>>(x, G, PHL, PHB, w_out, S, out, 2*m+1, b0, 2);
      k_stepH<false><<<2048,256,0,stream>>>(x, G, PHL, PHB, PH0, S, b0);
    }
    k_stepL<true><<<2048,256,0,stream>>>(x, G, PHL, PHB, w_out, S, out, 31, b0, 1);
  }
}